// Round 10
// baseline (289.353 us; speedup 1.0000x reference)
//
#include <hip/hip_runtime.h>
#include <hip/hip_bf16.h>

// NodeModel fused GNN block, round 10: isolate streaming vs scattered work.
//   memset cnt
//   prep_hist : weight transposes/folds + histogram
//   scanA/BC  : parallel exclusive scan -> offs
//   scatter_k : sre[pos] = (row,e)  (8B scattered writes -- proven cheap r2)
//   gemm_y    : Yb = bf16(x @ W1a_top + b1a)
//   edge_T    : TMP8[e] = fp8(ea[e] @ W1a_bot)     [PURE STREAMING, no y, no scatter]
//   node_R2   : mean_j = (1/m) sum relu(y[row_e] + t_e)  [ALL gathers here:
//               1 wave/node, no barriers, max TLP; TMP8 L3-resident, Yb L2-resident]
//   mlp_h1out : out = relu(x@W2c + mean@W2d + b2a + gate*bc + vtab[batch]) @ W2b + b2b

typedef __bf16 bf16x8 __attribute__((ext_vector_type(8)));
typedef float f32x4v __attribute__((ext_vector_type(4)));
typedef float f32x2v __attribute__((ext_vector_type(2)));
typedef unsigned int u32x2v __attribute__((ext_vector_type(2)));
typedef unsigned int u32x4v __attribute__((ext_vector_type(4)));

#define NN 40000
#define NE 640000

__device__ inline bf16x8 cvt8(const float* __restrict__ p) {
  f32x4v a = *(const f32x4v*)p;
  f32x4v b = *(const f32x4v*)(p + 4);
  bf16x8 r;
  r[0] = (__bf16)a[0]; r[1] = (__bf16)a[1]; r[2] = (__bf16)a[2]; r[3] = (__bf16)a[3];
  r[4] = (__bf16)b[0]; r[5] = (__bf16)b[1]; r[6] = (__bf16)b[2]; r[7] = (__bf16)b[3];
  return r;
}

__device__ inline float blo(unsigned u) { return __builtin_bit_cast(float, u << 16); }
__device__ inline float bhi(unsigned u) { return __builtin_bit_cast(float, u & 0xffff0000u); }

// ================= prep (blocks 0..384) + histogram (385..2884) =============
__global__ __launch_bounds__(256) void prep_hist(
    const float* __restrict__ W1a, const float* __restrict__ W2a,
    const float* __restrict__ W2b, const float* __restrict__ W1b,
    const float* __restrict__ b1b, const float* __restrict__ u,
    const int* __restrict__ EI,
    __bf16* __restrict__ WTya, __bf16* __restrict__ WTeb,
    __bf16* __restrict__ WT2c, __bf16* __restrict__ WT2bT,
    __bf16* __restrict__ WT2d, float* __restrict__ vtab,
    float* __restrict__ bc, int* __restrict__ cnt)
{
  int b = blockIdx.x, t = threadIdx.x;
  if (b >= 385) {                     // histogram: 2500 blocks cover NE
    int e = (b - 385) * 256 + t;
    atomicAdd(&cnt[EI[NE + e]], 1);
    return;
  }
  if (b < 64) {
    int idx = b * 256 + t; int n = idx & 127; int k = idx >> 7;
    WTya[n * 128 + k] = (__bf16)W1a[k * 128 + n];
  } else if (b < 96) {
    int idx = (b - 64) * 256 + t; int n = idx & 127; int k = idx >> 7;
    WTeb[n * 64 + k] = (__bf16)W1a[(128 + k) * 128 + n];
  } else if (b < 160) {
    int idx = (b - 96) * 256 + t; int n = idx & 127; int k = idx >> 7;
    WT2c[n * 128 + k] = (__bf16)W2a[k * 128 + n];
  } else if (b < 224) {
    int idx = (b - 160) * 256 + t; int n = idx & 127; int k = idx >> 7;
    WT2bT[n * 128 + k] = (__bf16)W2b[k * 128 + n];
  } else if (b < 256) {
    int idx = (b - 224) * 256 + t; int n = idx & 127; int gi = idx >> 7;
    float s = 0.f;
    for (int k = 0; k < 64; ++k) s += u[gi * 64 + k] * W2a[(256 + k) * 128 + n];
    vtab[gi * 128 + n] = s;
  } else if (b == 256) {
    if (t < 128) {
      float s = 0.f;
      for (int j = 0; j < 128; ++j) s += b1b[j] * W2a[(128 + j) * 128 + t];
      bc[t] = s;
    }
  } else {
    int k = b - 257;
    if (t < 128) {
      float s = 0.f;
      for (int j = 0; j < 128; ++j) s += W1b[k * 128 + j] * W2a[(128 + j) * 128 + t];
      WT2d[t * 128 + k] = (__bf16)s;
    }
  }
}

// ================= parallel scan: A (block-local) + BC (add base) ===========
__global__ __launch_bounds__(256) void scanA(const int* __restrict__ cnt,
                                             int* __restrict__ offs,
                                             int* __restrict__ bsum) {
  __shared__ int sc[256];
  int i = blockIdx.x * 256 + threadIdx.x;
  int v = (i < NN) ? cnt[i] : 0;
  sc[threadIdx.x] = v;
  __syncthreads();
  for (int off = 1; off < 256; off <<= 1) {
    int t2 = (threadIdx.x >= off) ? sc[threadIdx.x - off] : 0;
    __syncthreads();
    sc[threadIdx.x] += t2;
    __syncthreads();
  }
  if (i < NN) offs[i] = sc[threadIdx.x] - v;      // exclusive within block
  if (threadIdx.x == 255) bsum[blockIdx.x] = sc[255];
}

__global__ __launch_bounds__(256) void scanBC(int* __restrict__ offs,
                                              const int* __restrict__ bsum) {
  __shared__ int sc[256];
  int t = threadIdx.x;
  sc[t] = (t < 157) ? bsum[t] : 0;
  __syncthreads();
  for (int off = 1; off < 256; off <<= 1) {
    int t2 = (t >= off) ? sc[t - off] : 0;
    __syncthreads();
    sc[t] += t2;
    __syncthreads();
  }
  int base = (blockIdx.x > 0) ? sc[blockIdx.x - 1] : 0;   // inclusive -> excl
  int i = blockIdx.x * 256 + t;
  if (i < NN) offs[i] += base;
}

// ================= scatter: sre[slot] = (row, edge-id) ======================
__global__ __launch_bounds__(256) void scatter_k(const int* __restrict__ EI,
                                                 int* __restrict__ offs,
                                                 unsigned long long* __restrict__ sre) {
  int e = blockIdx.x * 256 + threadIdx.x;   // grid covers NE exactly
  int col = EI[NE + e];
  int row = EI[e];
  int pos = atomicAdd(&offs[col], 1);       // offs -> END offsets
  sre[pos] = ((unsigned long long)(unsigned)row << 32) | (unsigned)e;
}

// ================= y-GEMM: Yb = bf16(x @ WTya^T + b1a) ======================
__global__ __launch_bounds__(256) void gemm_y(
    const float* __restrict__ x, const __bf16* __restrict__ WTya,
    const float* __restrict__ b1a, __bf16* __restrict__ Yb)
{
  int lane = threadIdx.x & 63;
  int wave = threadIdx.x >> 6;
  int rowbase = blockIdx.x * 64 + wave * 16;
  int g = lane >> 4, c = lane & 15;

  f32x4v acc[8];
#pragma unroll
  for (int nt = 0; nt < 8; ++nt) acc[nt] = (f32x4v)(0.f);

  const float* arow = x + (size_t)(rowbase + c) * 128;
#pragma unroll
  for (int kk = 0; kk < 128; kk += 32) {
    bf16x8 af = cvt8(arow + kk + g * 8);
#pragma unroll
    for (int nt = 0; nt < 8; ++nt) {
      bf16x8 bf = *(const bf16x8*)(WTya + (nt * 16 + c) * 128 + kk + g * 8);
      acc[nt] = __builtin_amdgcn_mfma_f32_16x16x32_bf16(af, bf, acc[nt], 0, 0, 0);
    }
  }
#pragma unroll
  for (int q = 0; q < 4; ++q) {
    int r = rowbase + g * 4 + q;
#pragma unroll
    for (int nt = 0; nt < 8; ++nt) {
      int n = nt * 16 + c;
      Yb[(size_t)r * 128 + n] = (__bf16)(acc[nt][q] + b1a[n]);
    }
  }
}

// ================= edge_T: PURE STREAMING edge GEMM -> fp8 t ================
// 256 thr = 4 waves x 16 edges = 64 edges/block; reads EA coalesced,
// writes TMP8 rows in original edge order (contiguous 8KB per block).
__global__ __launch_bounds__(256) void edge_T(
    const float* __restrict__ EA,
    const __bf16* __restrict__ WTeb,
    unsigned char* __restrict__ TMP8)
{
  __shared__ __bf16 vb16[64 * 136];
  int t = threadIdx.x;
  int i0 = blockIdx.x * 64;
  int lane = t & 63, w = t >> 6, g = lane >> 4, c = lane & 15;

  f32x4v acc[8];
#pragma unroll
  for (int nt = 0; nt < 8; ++nt) acc[nt] = (f32x4v)(0.f);

  const float* arow = EA + (size_t)(i0 + w * 16 + c) * 64;
#pragma unroll
  for (int kk = 0; kk < 64; kk += 32) {
    bf16x8 af = cvt8(arow + kk + g * 8);
#pragma unroll
    for (int nt = 0; nt < 8; ++nt) {
      bf16x8 bf = *(const bf16x8*)(WTeb + (nt * 16 + c) * 64 + kk + g * 8);
      acc[nt] = __builtin_amdgcn_mfma_f32_16x16x32_bf16(af, bf, acc[nt], 0, 0, 0);
    }
  }

#pragma unroll
  for (int q = 0; q < 4; ++q) {
    int r = w * 16 + g * 4 + q;
#pragma unroll
    for (int nt = 0; nt < 8; ++nt)
      vb16[r * 136 + nt * 16 + c] = (__bf16)acc[nt][q];
  }
  __syncthreads();

  // fp8-encode + STREAMING 128B-row stores (block writes 8KB contiguous)
#pragma unroll
  for (int k2 = 0; k2 < 2; ++k2) {
    int flat = t + k2 * 256;            // 0..511
    int row = flat >> 3, c16 = flat & 7;
    const __bf16* src = vb16 + row * 136 + c16 * 16;
    u32x4v a = *(const u32x4v*)src;
    u32x4v b = *(const u32x4v*)(src + 8);
    u32x4v o;
    o[0] = __builtin_amdgcn_cvt_pk_fp8_f32(blo(a[0]), bhi(a[0]), 0, false);
    o[0] = __builtin_amdgcn_cvt_pk_fp8_f32(blo(a[1]), bhi(a[1]), o[0], true);
    o[1] = __builtin_amdgcn_cvt_pk_fp8_f32(blo(a[2]), bhi(a[2]), 0, false);
    o[1] = __builtin_amdgcn_cvt_pk_fp8_f32(blo(a[3]), bhi(a[3]), o[1], true);
    o[2] = __builtin_amdgcn_cvt_pk_fp8_f32(blo(b[0]), bhi(b[0]), 0, false);
    o[2] = __builtin_amdgcn_cvt_pk_fp8_f32(blo(b[1]), bhi(b[1]), o[2], true);
    o[3] = __builtin_amdgcn_cvt_pk_fp8_f32(blo(b[2]), bhi(b[2]), 0, false);
    o[3] = __builtin_amdgcn_cvt_pk_fp8_f32(blo(b[3]), bhi(b[3]), o[3], true);
    *(u32x4v*)(TMP8 + (size_t)(i0 + row) * 128 + c16 * 16) = o;
  }
}

// ================= node_R2: per-node gather + relu(y+t) + mean ==============
// 1 wave per node (4/block), no barriers. lane = (edge-parity p, u32-col cu).
__global__ __launch_bounds__(256) void node_R2(
    const unsigned int* __restrict__ TMP32,      // fp8 t rows (32 u32 each)
    const unsigned long long* __restrict__ sre,  // (row,e) per sorted slot
    const __bf16* __restrict__ Yb,
    const int* __restrict__ cnt,
    const int* __restrict__ offs,                // END offsets
    __bf16* __restrict__ meanb)
{
  int node = blockIdx.x * 4 + (threadIdx.x >> 6);
  int lane = threadIdx.x & 63;
  int p = lane >> 5;               // which edge of the pair
  int cu = lane & 31;              // u32 column (4 feature cols)
  int m = cnt[node];
  int start = offs[node] - m;
  float a0 = 0.f, a1 = 0.f, a2 = 0.f, a3 = 0.f;
  int iters = (m + 1) >> 1;
  for (int j = 0; j < iters; ++j) {
    int es = 2 * j + p;
    if (es < m) {
      unsigned long long re = sre[start + es];
      unsigned e = (unsigned)re;
      unsigned row = (unsigned)(re >> 32);
      unsigned tt = TMP32[(size_t)e * 32 + cu];            // 128B coalesced/row
      f32x2v lo = __builtin_amdgcn_cvt_pk_f32_fp8(tt, false);
      f32x2v hi = __builtin_amdgcn_cvt_pk_f32_fp8(tt, true);
      u32x2v yp = *(const u32x2v*)(Yb + (size_t)row * 128 + cu * 4); // 8B
      a0 += fmaxf(lo[0] + blo(yp[0]), 0.f);
      a1 += fmaxf(lo[1] + bhi(yp[0]), 0.f);
      a2 += fmaxf(hi[0] + blo(yp[1]), 0.f);
      a3 += fmaxf(hi[1] + bhi(yp[1]), 0.f);
    }
  }
  a0 += __shfl_xor(a0, 32);
  a1 += __shfl_xor(a1, 32);
  a2 += __shfl_xor(a2, 32);
  a3 += __shfl_xor(a3, 32);
  if (p == 0) {
    float inv = 1.f / fmaxf((float)m, 1.f);
    a0 *= inv; a1 *= inv; a2 *= inv; a3 *= inv;
    unsigned p0 = ((unsigned)__builtin_bit_cast(unsigned short, (__bf16)a0)) |
                  ((unsigned)__builtin_bit_cast(unsigned short, (__bf16)a1) << 16);
    unsigned p1 = ((unsigned)__builtin_bit_cast(unsigned short, (__bf16)a2)) |
                  ((unsigned)__builtin_bit_cast(unsigned short, (__bf16)a3) << 16);
    u32x2v pk; pk[0] = p0; pk[1] = p1;
    *(u32x2v*)(meanb + (size_t)node * 128 + cu * 4) = pk;
  }
}

// ================= fused h1 + out GEMM ======================================
__global__ __launch_bounds__(256) void mlp_h1out(
    const float* __restrict__ x, const __bf16* __restrict__ meanb,
    const __bf16* __restrict__ WT2c, const __bf16* __restrict__ WT2d,
    const __bf16* __restrict__ WT2bT,
    const int* __restrict__ cnt, const float* __restrict__ b2a,
    const float* __restrict__ bc, const float* __restrict__ vtab,
    const int* __restrict__ batch, const float* __restrict__ b2b,
    float* __restrict__ out)
{
  __shared__ __bf16 ht[64 * 136];
  int lane = threadIdx.x & 63;
  int w = threadIdx.x >> 6;
  int rowbase = blockIdx.x * 64 + w * 16;
  int g = lane >> 4, c = lane & 15;

  f32x4v acc[8];
#pragma unroll
  for (int nt = 0; nt < 8; ++nt) acc[nt] = (f32x4v)(0.f);

  const float* arow = x + (size_t)(rowbase + c) * 128;
#pragma unroll
  for (int kk = 0; kk < 128; kk += 32) {
    bf16x8 af = cvt8(arow + kk + g * 8);
#pragma unroll
    for (int nt = 0; nt < 8; ++nt) {
      bf16x8 bf = *(const bf16x8*)(WT2c + (nt * 16 + c) * 128 + kk + g * 8);
      acc[nt] = __builtin_amdgcn_mfma_f32_16x16x32_bf16(af, bf, acc[nt], 0, 0, 0);
    }
  }
  const __bf16* arow2 = meanb + (size_t)(rowbase + c) * 128;
#pragma unroll
  for (int kk = 0; kk < 128; kk += 32) {
    bf16x8 af = *(const bf16x8*)(arow2 + kk + g * 8);
#pragma unroll
    for (int nt = 0; nt < 8; ++nt) {
      bf16x8 bf = *(const bf16x8*)(WT2d + (nt * 16 + c) * 128 + kk + g * 8);
      acc[nt] = __builtin_amdgcn_mfma_f32_16x16x32_bf16(af, bf, acc[nt], 0, 0, 0);
    }
  }

#pragma unroll
  for (int q = 0; q < 4; ++q) {
    int r = rowbase + g * 4 + q;
    float gmul = cnt[r] ? 1.f : 0.f;
    const float* vrow = vtab + (size_t)batch[r] * 128;
#pragma unroll
    for (int nt = 0; nt < 8; ++nt) {
      int n = nt * 16 + c;
      float v = acc[nt][q] + b2a[n] + gmul * bc[n] + vrow[n];
      ht[(w * 16 + g * 4 + q) * 136 + n] = (__bf16)fmaxf(v, 0.f);
    }
  }
  __syncthreads();

  f32x4v acc2[8];
#pragma unroll
  for (int nt = 0; nt < 8; ++nt) acc2[nt] = (f32x4v)(0.f);

  const __bf16* hrow = ht + (w * 16 + c) * 136;
#pragma unroll
  for (int kk = 0; kk < 128; kk += 32) {
    bf16x8 af = *(const bf16x8*)(hrow + kk + g * 8);
#pragma unroll
    for (int nt = 0; nt < 8; ++nt) {
      bf16x8 bf = *(const bf16x8*)(WT2bT + (nt * 16 + c) * 128 + kk + g * 8);
      acc2[nt] = __builtin_amdgcn_mfma_f32_16x16x32_bf16(af, bf, acc2[nt], 0, 0, 0);
    }
  }
#pragma unroll
  for (int q = 0; q < 4; ++q) {
    int r = rowbase + g * 4 + q;
#pragma unroll
    for (int nt = 0; nt < 8; ++nt) {
      int n = nt * 16 + c;
      out[(size_t)r * 128 + n] = acc2[nt][q] + b2b[n];
    }
  }
}

// ================= host =====================================================
extern "C" void kernel_launch(void* const* d_in, const int* in_sizes, int n_in,
                              void* d_out, int out_size, void* d_ws, size_t ws_size,
                              hipStream_t stream) {
  const float* x    = (const float*)d_in[0];
  const int*   ei   = (const int*)d_in[1];
  const float* ea   = (const float*)d_in[2];
  const float* u    = (const float*)d_in[3];
  const int*   batch= (const int*)d_in[4];
  const float* W1a  = (const float*)d_in[5];
  const float* b1a  = (const float*)d_in[6];
  const float* W1b  = (const float*)d_in[7];
  const float* b1b  = (const float*)d_in[8];
  const float* W2a  = (const float*)d_in[9];
  const float* b2a  = (const float*)d_in[10];
  const float* W2b  = (const float*)d_in[11];
  const float* b2b  = (const float*)d_in[12];

  char* ws = (char*)d_ws;
  __bf16* WTya  = (__bf16*)(ws);              // 32768
  __bf16* WTeb  = (__bf16*)(ws + 32768);      // 16384
  __bf16* WT2c  = (__bf16*)(ws + 49152);      // 32768
  __bf16* WT2bT = (__bf16*)(ws + 81920);      // 32768
  __bf16* WT2d  = (__bf16*)(ws + 114688);     // 32768
  float*  vtab  = (float*)(ws + 147456);      // 32768
  float*  bc    = (float*)(ws + 180224);      // 512
  int*    cnt   = (int*)(ws + 180736);        // 160,000
  int*    offs  = (int*)(ws + 340736);        // 160,000
  int*    bsum  = (int*)(ws + 500736);        // 1,024
  unsigned long long* sre = (unsigned long long*)(ws + 502784); // 5,120,000
  __bf16* Yb    = (__bf16*)(ws + 5622784);    // 10,240,000
  unsigned char* TMP8 = (unsigned char*)(ws + 15862784); // 81,920,000
  __bf16* meanb = (__bf16*)(ws + 97782784);   // 10,240,000 -> end 108.0 MB
  // (proven ws >= 118 MB in rounds 3-5)

  hipMemsetAsync(cnt, 0, 160000, stream);
  prep_hist<<<2885, 256, 0, stream>>>(W1a, W2a, W2b, W1b, b1b, u, ei,
                                      WTya, WTeb, WT2c, WT2bT, WT2d,
                                      vtab, bc, cnt);
  scanA<<<157, 256, 0, stream>>>(cnt, offs, bsum);
  scanBC<<<157, 256, 0, stream>>>(offs, bsum);
  scatter_k<<<2500, 256, 0, stream>>>(ei, offs, sre);
  gemm_y<<<625, 256, 0, stream>>>(x, WTya, b1a, Yb);
  edge_T<<<NE / 64, 256, 0, stream>>>(ea, WTeb, TMP8);
  node_R2<<<NN / 4, 256, 0, stream>>>((const unsigned int*)TMP8, sre, Yb,
                                      cnt, offs, meanb);
  mlp_h1out<<<625, 256, 0, stream>>>(x, meanb, WT2c, WT2d, WT2bT,
                                     cnt, b2a, bc, vtab, batch, b2b,
                                     (float*)d_out);
}

// Round 11
// 243.747 us; speedup vs baseline: 1.1871x; 1.1871x over previous
//
#include <hip/hip_runtime.h>
#include <hip/hip_bf16.h>

// NodeModel fused GNN block, round 11 = round 8 structure + fragment-native
// permuted layout: TMP8/Yb/meanb store feature pi(j)=(j&7)*16+(j>>3) at pos j,
// making every MFMA-lane's 8 output values contiguous -> edge_E has NO LDS and
// NO barriers (direct reg->fp8->8B stores, direct 16B y-gathers). node_R is
// elementwise (layout-agnostic); only WT2d's k-index is permuted in prep.
//   memset cnt; prep_hist; scanA/BC; gemm_y; edge_E; node_R; mlp_h1out

typedef __bf16 bf16x8 __attribute__((ext_vector_type(8)));
typedef float f32x4v __attribute__((ext_vector_type(4)));
typedef float f32x2v __attribute__((ext_vector_type(2)));
typedef unsigned int u32x2v __attribute__((ext_vector_type(2)));

#define NN 40000
#define NE 640000

__device__ inline bf16x8 cvt8(const float* __restrict__ p) {
  f32x4v a = *(const f32x4v*)p;
  f32x4v b = *(const f32x4v*)(p + 4);
  bf16x8 r;
  r[0] = (__bf16)a[0]; r[1] = (__bf16)a[1]; r[2] = (__bf16)a[2]; r[3] = (__bf16)a[3];
  r[4] = (__bf16)b[0]; r[5] = (__bf16)b[1]; r[6] = (__bf16)b[2]; r[7] = (__bf16)b[3];
  return r;
}

// ================= prep (blocks 0..384) + histogram (385..2884) =============
__global__ __launch_bounds__(256) void prep_hist(
    const float* __restrict__ W1a, const float* __restrict__ W2a,
    const float* __restrict__ W2b, const float* __restrict__ W1b,
    const float* __restrict__ b1b, const float* __restrict__ u,
    const int* __restrict__ EI,
    __bf16* __restrict__ WTya, __bf16* __restrict__ WTeb,
    __bf16* __restrict__ WT2c, __bf16* __restrict__ WT2bT,
    __bf16* __restrict__ WT2d, float* __restrict__ vtab,
    float* __restrict__ bc, int* __restrict__ cnt)
{
  int b = blockIdx.x, t = threadIdx.x;
  if (b >= 385) {                     // histogram: 2500 blocks cover NE
    int e = (b - 385) * 256 + t;
    atomicAdd(&cnt[EI[NE + e]], 1);
    return;
  }
  if (b < 64) {
    int idx = b * 256 + t; int n = idx & 127; int k = idx >> 7;
    WTya[n * 128 + k] = (__bf16)W1a[k * 128 + n];
  } else if (b < 96) {
    int idx = (b - 64) * 256 + t; int n = idx & 127; int k = idx >> 7;
    WTeb[n * 64 + k] = (__bf16)W1a[(128 + k) * 128 + n];
  } else if (b < 160) {
    int idx = (b - 96) * 256 + t; int n = idx & 127; int k = idx >> 7;
    WT2c[n * 128 + k] = (__bf16)W2a[k * 128 + n];
  } else if (b < 224) {
    int idx = (b - 160) * 256 + t; int n = idx & 127; int k = idx >> 7;
    WT2bT[n * 128 + k] = (__bf16)W2b[k * 128 + n];
  } else if (b < 256) {
    int idx = (b - 224) * 256 + t; int n = idx & 127; int gi = idx >> 7;
    float s = 0.f;
    for (int k = 0; k < 64; ++k) s += u[gi * 64 + k] * W2a[(256 + k) * 128 + n];
    vtab[gi * 128 + n] = s;
  } else if (b == 256) {
    if (t < 128) {
      float s = 0.f;
      for (int j = 0; j < 128; ++j) s += b1b[j] * W2a[(128 + j) * 128 + t];
      bc[t] = s;
    }
  } else {
    int k = b - 257;                  // mean-feature index (pre-permute)
    if (t < 128) {
      float s = 0.f;
      for (int j = 0; j < 128; ++j) s += W1b[k * 128 + j] * W2a[(128 + j) * 128 + t];
      int kp = ((k & 15) << 3) | (k >> 4);   // inverse of pi: pi(kp) == k
      WT2d[t * 128 + kp] = (__bf16)s;
    }
  }
}

// ================= parallel scan: A (block-local) + BC (add base) ===========
__global__ __launch_bounds__(256) void scanA(const int* __restrict__ cnt,
                                             int* __restrict__ offs,
                                             int* __restrict__ bsum) {
  __shared__ int sc[256];
  int i = blockIdx.x * 256 + threadIdx.x;
  int v = (i < NN) ? cnt[i] : 0;
  sc[threadIdx.x] = v;
  __syncthreads();
  for (int off = 1; off < 256; off <<= 1) {
    int t2 = (threadIdx.x >= off) ? sc[threadIdx.x - off] : 0;
    __syncthreads();
    sc[threadIdx.x] += t2;
    __syncthreads();
  }
  if (i < NN) offs[i] = sc[threadIdx.x] - v;      // exclusive within block
  if (threadIdx.x == 255) bsum[blockIdx.x] = sc[255];
}

__global__ __launch_bounds__(256) void scanBC(int* __restrict__ offs,
                                              const int* __restrict__ bsum) {
  __shared__ int sc[256];
  int t = threadIdx.x;
  sc[t] = (t < 157) ? bsum[t] : 0;
  __syncthreads();
  for (int off = 1; off < 256; off <<= 1) {
    int t2 = (t >= off) ? sc[t - off] : 0;
    __syncthreads();
    sc[t] += t2;
    __syncthreads();
  }
  int base = (blockIdx.x > 0) ? sc[blockIdx.x - 1] : 0;   // inclusive -> excl
  int i = blockIdx.x * 256 + t;
  if (i < NN) offs[i] += base;
}

// ================= y-GEMM: Yb (pi-packed) = x @ W1a_top + b1a ===============
// lane (g,c) stores its 8 fragment cols (features nt*16+c) contiguously at
// position c*8..c*8+7 -> one bf16x8 store per q, 128B coalesced per 16 lanes.
__global__ __launch_bounds__(256) void gemm_y(
    const float* __restrict__ x, const __bf16* __restrict__ WTya,
    const float* __restrict__ b1a, __bf16* __restrict__ Yb)
{
  int lane = threadIdx.x & 63;
  int wave = threadIdx.x >> 6;
  int rowbase = blockIdx.x * 64 + wave * 16;
  int g = lane >> 4, c = lane & 15;

  f32x4v acc[8];
#pragma unroll
  for (int nt = 0; nt < 8; ++nt) acc[nt] = (f32x4v)(0.f);

  const float* arow = x + (size_t)(rowbase + c) * 128;
#pragma unroll
  for (int kk = 0; kk < 128; kk += 32) {
    bf16x8 af = cvt8(arow + kk + g * 8);
#pragma unroll
    for (int nt = 0; nt < 8; ++nt) {
      bf16x8 bf = *(const bf16x8*)(WTya + (nt * 16 + c) * 128 + kk + g * 8);
      acc[nt] = __builtin_amdgcn_mfma_f32_16x16x32_bf16(af, bf, acc[nt], 0, 0, 0);
    }
  }
  float bl[8];
#pragma unroll
  for (int nt = 0; nt < 8; ++nt) bl[nt] = b1a[nt * 16 + c];
#pragma unroll
  for (int q = 0; q < 4; ++q) {
    int r = rowbase + g * 4 + q;
    bf16x8 o;
#pragma unroll
    for (int nt = 0; nt < 8; ++nt) o[nt] = (__bf16)(acc[nt][q] + bl[nt]);
    *(bf16x8*)(Yb + (size_t)r * 128 + c * 8) = o;
  }
}

// ================= E: LDS-free edge GEMM + y-add + fp8 scattered store ======
// 4 waves x 16 edges per block; lanes 0..15 of each wave fetch edge meta and
// allocate sorted slots; everything else stays in registers. No barriers.
__global__ __launch_bounds__(256) void edge_E(
    const float* __restrict__ EA, const int* __restrict__ EI,
    int* __restrict__ offs,              // mutates to END offsets
    const __bf16* __restrict__ WTeb,
    const __bf16* __restrict__ Yb,       // pi-packed
    unsigned char* __restrict__ TMP8)    // 640000 x 128 fp8, pi-packed rows
{
  int t = threadIdx.x;
  int lane = t & 63, w = t >> 6;
  int e0 = blockIdx.x * 64 + w * 16;     // this wave's 16 edges
  int g = lane >> 4, c = lane & 15;

  int myrow = 0, mypos = 0;
  if (lane < 16) {
    myrow = EI[e0 + lane];
    int col = EI[NE + e0 + lane];
    mypos = atomicAdd(&offs[col], 1);    // fused scatter slot alloc
  }

  f32x4v acc[8];
#pragma unroll
  for (int nt = 0; nt < 8; ++nt) acc[nt] = (f32x4v)(0.f);

  const float* arow = EA + (size_t)(e0 + c) * 64;
#pragma unroll
  for (int kk = 0; kk < 64; kk += 32) {
    bf16x8 af = cvt8(arow + kk + g * 8);
#pragma unroll
    for (int nt = 0; nt < 8; ++nt) {
      bf16x8 bf = *(const bf16x8*)(WTeb + (nt * 16 + c) * 64 + kk + g * 8);
      acc[nt] = __builtin_amdgcn_mfma_f32_16x16x32_bf16(af, bf, acc[nt], 0, 0, 0);
    }
  }

#pragma unroll
  for (int q = 0; q < 4; ++q) {
    int src = g * 4 + q;                 // wave-edge owning lane
    int row = __shfl(myrow, src, 64);
    int pos = __shfl(mypos, src, 64);
    bf16x8 yv = *(const bf16x8*)(Yb + (size_t)row * 128 + c * 8);  // 16B gather
    float v0 = fmaxf(acc[0][q] + (float)yv[0], 0.f);
    float v1 = fmaxf(acc[1][q] + (float)yv[1], 0.f);
    float v2 = fmaxf(acc[2][q] + (float)yv[2], 0.f);
    float v3 = fmaxf(acc[3][q] + (float)yv[3], 0.f);
    float v4 = fmaxf(acc[4][q] + (float)yv[4], 0.f);
    float v5 = fmaxf(acc[5][q] + (float)yv[5], 0.f);
    float v6 = fmaxf(acc[6][q] + (float)yv[6], 0.f);
    float v7 = fmaxf(acc[7][q] + (float)yv[7], 0.f);
    unsigned lo = __builtin_amdgcn_cvt_pk_fp8_f32(v0, v1, 0, false);
    lo = __builtin_amdgcn_cvt_pk_fp8_f32(v2, v3, lo, true);
    unsigned hi = __builtin_amdgcn_cvt_pk_fp8_f32(v4, v5, 0, false);
    hi = __builtin_amdgcn_cvt_pk_fp8_f32(v6, v7, hi, true);
    u32x2v o; o[0] = lo; o[1] = hi;
    *(u32x2v*)(TMP8 + (size_t)pos * 128 + c * 8) = o;  // 8B, 128B/16-lane row
  }
}

// ================= R: streaming fp8 segment mean (2 rows / iter) ============
__global__ __launch_bounds__(256) void node_R(
    const unsigned int* __restrict__ TMP32,   // fp8 rows as 32 x u32
    const int* __restrict__ cnt,
    const int* __restrict__ offs,             // END offsets
    __bf16* __restrict__ meanb)               // pi-packed (elementwise)
{
  int node = blockIdx.x * 4 + (threadIdx.x >> 6);
  int lane = threadIdx.x & 63;
  int rowpar = lane >> 5;
  int cu = lane & 31;
  int m = cnt[node];
  int start = offs[node] - m;
  float s0 = 0.f, s1 = 0.f, s2 = 0.f, s3 = 0.f;
  int iters = (m + 1) >> 1;
  for (int j = 0; j < iters; ++j) {
    int r2 = 2 * j + rowpar;
    unsigned uu = (r2 < m) ? TMP32[(size_t)(start + r2) * 32 + cu] : 0u;
    f32x2v lo = __builtin_amdgcn_cvt_pk_f32_fp8(uu, false);
    f32x2v hi = __builtin_amdgcn_cvt_pk_f32_fp8(uu, true);
    s0 += lo[0]; s1 += lo[1]; s2 += hi[0]; s3 += hi[1];
  }
  s0 += __shfl_xor(s0, 32);
  s1 += __shfl_xor(s1, 32);
  s2 += __shfl_xor(s2, 32);
  s3 += __shfl_xor(s3, 32);
  if (rowpar == 0) {
    float inv = 1.f / fmaxf((float)m, 1.f);
    s0 *= inv; s1 *= inv; s2 *= inv; s3 *= inv;
    unsigned p0 = ((unsigned)__builtin_bit_cast(unsigned short, (__bf16)s0)) |
                  ((unsigned)__builtin_bit_cast(unsigned short, (__bf16)s1) << 16);
    unsigned p1 = ((unsigned)__builtin_bit_cast(unsigned short, (__bf16)s2)) |
                  ((unsigned)__builtin_bit_cast(unsigned short, (__bf16)s3) << 16);
    u32x2v pk; pk[0] = p0; pk[1] = p1;
    *(u32x2v*)(meanb + (size_t)node * 128 + cu * 4) = pk;
  }
}

// ================= fused h1 + out GEMM ======================================
// meanb is pi-packed; WT2d rows were k-permuted in prep to match.
__global__ __launch_bounds__(256) void mlp_h1out(
    const float* __restrict__ x, const __bf16* __restrict__ meanb,
    const __bf16* __restrict__ WT2c, const __bf16* __restrict__ WT2d,
    const __bf16* __restrict__ WT2bT,
    const int* __restrict__ cnt, const float* __restrict__ b2a,
    const float* __restrict__ bc, const float* __restrict__ vtab,
    const int* __restrict__ batch, const float* __restrict__ b2b,
    float* __restrict__ out)
{
  __shared__ __bf16 ht[64 * 136];
  int lane = threadIdx.x & 63;
  int w = threadIdx.x >> 6;
  int rowbase = blockIdx.x * 64 + w * 16;
  int g = lane >> 4, c = lane & 15;

  f32x4v acc[8];
#pragma unroll
  for (int nt = 0; nt < 8; ++nt) acc[nt] = (f32x4v)(0.f);

  const float* arow = x + (size_t)(rowbase + c) * 128;
#pragma unroll
  for (int kk = 0; kk < 128; kk += 32) {
    bf16x8 af = cvt8(arow + kk + g * 8);
#pragma unroll
    for (int nt = 0; nt < 8; ++nt) {
      bf16x8 bf = *(const bf16x8*)(WT2c + (nt * 16 + c) * 128 + kk + g * 8);
      acc[nt] = __builtin_amdgcn_mfma_f32_16x16x32_bf16(af, bf, acc[nt], 0, 0, 0);
    }
  }
  const __bf16* arow2 = meanb + (size_t)(rowbase + c) * 128;
#pragma unroll
  for (int kk = 0; kk < 128; kk += 32) {
    bf16x8 af = *(const bf16x8*)(arow2 + kk + g * 8);
#pragma unroll
    for (int nt = 0; nt < 8; ++nt) {
      bf16x8 bf = *(const bf16x8*)(WT2d + (nt * 16 + c) * 128 + kk + g * 8);
      acc[nt] = __builtin_amdgcn_mfma_f32_16x16x32_bf16(af, bf, acc[nt], 0, 0, 0);
    }
  }

#pragma unroll
  for (int q = 0; q < 4; ++q) {
    int r = rowbase + g * 4 + q;
    float gmul = cnt[r] ? 1.f : 0.f;
    const float* vrow = vtab + (size_t)batch[r] * 128;
#pragma unroll
    for (int nt = 0; nt < 8; ++nt) {
      int n = nt * 16 + c;
      float v = acc[nt][q] + b2a[n] + gmul * bc[n] + vrow[n];
      ht[(w * 16 + g * 4 + q) * 136 + n] = (__bf16)fmaxf(v, 0.f);
    }
  }
  __syncthreads();

  f32x4v acc2[8];
#pragma unroll
  for (int nt = 0; nt < 8; ++nt) acc2[nt] = (f32x4v)(0.f);

  const __bf16* hrow = ht + (w * 16 + c) * 136;
#pragma unroll
  for (int kk = 0; kk < 128; kk += 32) {
    bf16x8 af = *(const bf16x8*)(hrow + kk + g * 8);
#pragma unroll
    for (int nt = 0; nt < 8; ++nt) {
      bf16x8 bf = *(const bf16x8*)(WT2bT + (nt * 16 + c) * 128 + kk + g * 8);
      acc2[nt] = __builtin_amdgcn_mfma_f32_16x16x32_bf16(af, bf, acc2[nt], 0, 0, 0);
    }
  }
#pragma unroll
  for (int q = 0; q < 4; ++q) {
    int r = rowbase + g * 4 + q;
#pragma unroll
    for (int nt = 0; nt < 8; ++nt) {
      int n = nt * 16 + c;
      out[(size_t)r * 128 + n] = acc2[nt][q] + b2b[n];
    }
  }
}

// ================= host =====================================================
extern "C" void kernel_launch(void* const* d_in, const int* in_sizes, int n_in,
                              void* d_out, int out_size, void* d_ws, size_t ws_size,
                              hipStream_t stream) {
  const float* x    = (const float*)d_in[0];
  const int*   ei   = (const int*)d_in[1];
  const float* ea   = (const float*)d_in[2];
  const float* u    = (const float*)d_in[3];
  const int*   batch= (const int*)d_in[4];
  const float* W1a  = (const float*)d_in[5];
  const float* b1a  = (const float*)d_in[6];
  const float* W1b  = (const float*)d_in[7];
  const float* b1b  = (const float*)d_in[8];
  const float* W2a  = (const float*)d_in[9];
  const float* b2a  = (const float*)d_in[10];
  const float* W2b  = (const float*)d_in[11];
  const float* b2b  = (const float*)d_in[12];

  char* ws = (char*)d_ws;
  __bf16* WTya  = (__bf16*)(ws);              // 32768
  __bf16* WTeb  = (__bf16*)(ws + 32768);      // 16384
  __bf16* WT2c  = (__bf16*)(ws + 49152);      // 32768
  __bf16* WT2bT = (__bf16*)(ws + 81920);      // 32768
  __bf16* WT2d  = (__bf16*)(ws + 114688);     // 32768
  float*  vtab  = (float*)(ws + 147456);      // 32768
  float*  bc    = (float*)(ws + 180224);      // 512
  int*    cnt   = (int*)(ws + 180736);        // 160,000
  int*    offs  = (int*)(ws + 340736);        // 160,000
  int*    bsum  = (int*)(ws + 500736);        // 1,024
  __bf16* Yb    = (__bf16*)(ws + 3061760);    // 10,240,000 (then meanb)
  unsigned char* TMP8 = (unsigned char*)(ws + 13301760); // 81,920,000 -> 95.2 MB
  __bf16* meanb = Yb;

  hipMemsetAsync(cnt, 0, 160000, stream);
  prep_hist<<<2885, 256, 0, stream>>>(W1a, W2a, W2b, W1b, b1b, u, ei,
                                      WTya, WTeb, WT2c, WT2bT, WT2d,
                                      vtab, bc, cnt);
  scanA<<<157, 256, 0, stream>>>(cnt, offs, bsum);
  scanBC<<<157, 256, 0, stream>>>(offs, bsum);
  gemm_y<<<625, 256, 0, stream>>>(x, WTya, b1a, Yb);
  edge_E<<<NE / 64, 256, 0, stream>>>(ea, ei, offs, WTeb, Yb, TMP8);
  node_R<<<NN / 4, 256, 0, stream>>>((const unsigned int*)TMP8, cnt, offs, meanb);
  mlp_h1out<<<625, 256, 0, stream>>>(x, meanb, WT2c, WT2d, WT2bT,
                                     cnt, b2a, bc, vtab, batch, b2b,
                                     (float*)d_out);
}

// Round 12
// 227.142 us; speedup vs baseline: 1.2739x; 1.0731x over previous
//
#include <hip/hip_runtime.h>
#include <hip/hip_bf16.h>

// NodeModel fused GNN block, round 12 = round 11 + dense-load LDS staging in
// edge_E (lane-CONTIGUOUS EA reads -> padded LDS -> ds_read_b128 fragments),
// fused scanBC+gemm_y launch, 4-row node_R.
//   memset cnt; prep_hist; scanA; [scanBC|gemm_y]; edge_E; node_R; mlp_h1out

typedef __bf16 bf16x8 __attribute__((ext_vector_type(8)));
typedef float f32x4v __attribute__((ext_vector_type(4)));
typedef float f32x2v __attribute__((ext_vector_type(2)));
typedef unsigned int u32x2v __attribute__((ext_vector_type(2)));

#define NN 40000
#define NE 640000

__device__ inline bf16x8 cvt8(const float* __restrict__ p) {
  f32x4v a = *(const f32x4v*)p;
  f32x4v b = *(const f32x4v*)(p + 4);
  bf16x8 r;
  r[0] = (__bf16)a[0]; r[1] = (__bf16)a[1]; r[2] = (__bf16)a[2]; r[3] = (__bf16)a[3];
  r[4] = (__bf16)b[0]; r[5] = (__bf16)b[1]; r[6] = (__bf16)b[2]; r[7] = (__bf16)b[3];
  return r;
}

// ================= prep (blocks 0..384) + histogram (385..2884) =============
__global__ __launch_bounds__(256) void prep_hist(
    const float* __restrict__ W1a, const float* __restrict__ W2a,
    const float* __restrict__ W2b, const float* __restrict__ W1b,
    const float* __restrict__ b1b, const float* __restrict__ u,
    const int* __restrict__ EI,
    __bf16* __restrict__ WTya, __bf16* __restrict__ WTeb,
    __bf16* __restrict__ WT2c, __bf16* __restrict__ WT2bT,
    __bf16* __restrict__ WT2d, float* __restrict__ vtab,
    float* __restrict__ bc, int* __restrict__ cnt)
{
  int b = blockIdx.x, t = threadIdx.x;
  if (b >= 385) {                     // histogram: 2500 blocks cover NE
    int e = (b - 385) * 256 + t;
    atomicAdd(&cnt[EI[NE + e]], 1);
    return;
  }
  if (b < 64) {
    int idx = b * 256 + t; int n = idx & 127; int k = idx >> 7;
    WTya[n * 128 + k] = (__bf16)W1a[k * 128 + n];
  } else if (b < 96) {
    int idx = (b - 64) * 256 + t; int n = idx & 127; int k = idx >> 7;
    WTeb[n * 64 + k] = (__bf16)W1a[(128 + k) * 128 + n];
  } else if (b < 160) {
    int idx = (b - 96) * 256 + t; int n = idx & 127; int k = idx >> 7;
    WT2c[n * 128 + k] = (__bf16)W2a[k * 128 + n];
  } else if (b < 224) {
    int idx = (b - 160) * 256 + t; int n = idx & 127; int k = idx >> 7;
    WT2bT[n * 128 + k] = (__bf16)W2b[k * 128 + n];
  } else if (b < 256) {
    int idx = (b - 224) * 256 + t; int n = idx & 127; int gi = idx >> 7;
    float s0 = 0.f, s1 = 0.f;
    for (int k = 0; k < 64; k += 2) {
      s0 += u[gi * 64 + k] * W2a[(256 + k) * 128 + n];
      s1 += u[gi * 64 + k + 1] * W2a[(257 + k) * 128 + n];
    }
    vtab[gi * 128 + n] = s0 + s1;
  } else if (b == 256) {
    if (t < 128) {
      float s0 = 0.f, s1 = 0.f;
      for (int j = 0; j < 128; j += 2) {
        s0 += b1b[j] * W2a[(128 + j) * 128 + t];
        s1 += b1b[j + 1] * W2a[(129 + j) * 128 + t];
      }
      bc[t] = s0 + s1;
    }
  } else {
    int k = b - 257;                  // mean-feature index (pre-permute)
    if (t < 128) {
      float s0 = 0.f, s1 = 0.f;
      for (int j = 0; j < 128; j += 2) {
        s0 += W1b[k * 128 + j] * W2a[(128 + j) * 128 + t];
        s1 += W1b[k * 128 + j + 1] * W2a[(129 + j) * 128 + t];
      }
      int kp = ((k & 15) << 3) | (k >> 4);   // inverse of pi: pi(kp) == k
      WT2d[t * 128 + kp] = (__bf16)(s0 + s1);
    }
  }
}

// ================= scanA: block-local exclusive scan + block sums ===========
__global__ __launch_bounds__(256) void scanA(const int* __restrict__ cnt,
                                             int* __restrict__ offs,
                                             int* __restrict__ bsum) {
  __shared__ int sc[256];
  int i = blockIdx.x * 256 + threadIdx.x;
  int v = (i < NN) ? cnt[i] : 0;
  sc[threadIdx.x] = v;
  __syncthreads();
  for (int off = 1; off < 256; off <<= 1) {
    int t2 = (threadIdx.x >= off) ? sc[threadIdx.x - off] : 0;
    __syncthreads();
    sc[threadIdx.x] += t2;
    __syncthreads();
  }
  if (i < NN) offs[i] = sc[threadIdx.x] - v;      // exclusive within block
  if (threadIdx.x == 255) bsum[blockIdx.x] = sc[255];
}

// ================= fused: scanBC (blocks 0..156) | gemm_y (157..781) ========
__global__ __launch_bounds__(256) void scanBC_gemmy(
    int* __restrict__ offs, const int* __restrict__ bsum,
    const float* __restrict__ x, const __bf16* __restrict__ WTya,
    const float* __restrict__ b1a, __bf16* __restrict__ Yb)
{
  __shared__ int sc[256];
  if (blockIdx.x < 157) {
    int t = threadIdx.x;
    sc[t] = (t < 157) ? bsum[t] : 0;
    __syncthreads();
    for (int off = 1; off < 256; off <<= 1) {
      int t2 = (t >= off) ? sc[t - off] : 0;
      __syncthreads();
      sc[t] += t2;
      __syncthreads();
    }
    int base = (blockIdx.x > 0) ? sc[blockIdx.x - 1] : 0;
    int i = blockIdx.x * 256 + t;
    if (i < NN) offs[i] += base;
    return;
  }
  // ---- gemm_y: Yb (pi-packed) = x @ W1a_top + b1a ----
  int lane = threadIdx.x & 63;
  int wave = threadIdx.x >> 6;
  int rowbase = (blockIdx.x - 157) * 64 + wave * 16;
  int g = lane >> 4, c = lane & 15;

  f32x4v acc[8];
#pragma unroll
  for (int nt = 0; nt < 8; ++nt) acc[nt] = (f32x4v)(0.f);

  const float* arow = x + (size_t)(rowbase + c) * 128;
#pragma unroll
  for (int kk = 0; kk < 128; kk += 32) {
    bf16x8 af = cvt8(arow + kk + g * 8);
#pragma unroll
    for (int nt = 0; nt < 8; ++nt) {
      bf16x8 bf = *(const bf16x8*)(WTya + (nt * 16 + c) * 128 + kk + g * 8);
      acc[nt] = __builtin_amdgcn_mfma_f32_16x16x32_bf16(af, bf, acc[nt], 0, 0, 0);
    }
  }
  float bl[8];
#pragma unroll
  for (int nt = 0; nt < 8; ++nt) bl[nt] = b1a[nt * 16 + c];
#pragma unroll
  for (int q = 0; q < 4; ++q) {
    int r = rowbase + g * 4 + q;
    bf16x8 o;
#pragma unroll
    for (int nt = 0; nt < 8; ++nt) o[nt] = (__bf16)(acc[nt][q] + bl[nt]);
    *(bf16x8*)(Yb + (size_t)r * 128 + c * 8) = o;
  }
}

// ================= E: dense-staged edge GEMM + fp8 scattered store ==========
// 256 thr, 64 edges/block. Stage: lane-CONTIGUOUS EA loads (thread t reads
// 32B at tile+t*32, dense 1KB/instruction) -> bf16 -> padded LDS [64][136].
// Fragments via ds_read_b128 (2-way bank alias = free). Epilogue reg-native.
__global__ __launch_bounds__(256) void edge_E(
    const float* __restrict__ EA, const int* __restrict__ EI,
    int* __restrict__ offs,              // mutates to END offsets
    const __bf16* __restrict__ WTeb,
    const __bf16* __restrict__ Yb,       // pi-packed
    unsigned char* __restrict__ TMP8)    // 640000 x 128 fp8, pi-packed rows
{
  __shared__ __bf16 sm[64 * 136];
  int t = threadIdx.x;
  int lane = t & 63, w = t >> 6;
  int e0 = blockIdx.x * 64 + w * 16;     // this wave's 16 edges
  int g = lane >> 4, c = lane & 15;

  int myrow = 0, mypos = 0;
  if (lane < 16) {
    myrow = EI[e0 + lane];
    int col = EI[NE + e0 + lane];
    mypos = atomicAdd(&offs[col], 1);    // fused scatter slot alloc
  }

  // dense stage: 2 iters x 256 thr x 32B = 16KB tile (64 edges x 256B)
  const float* tile = EA + (size_t)blockIdx.x * 64 * 64;
#pragma unroll
  for (int i = 0; i < 2; ++i) {
    int row = i * 32 + (t >> 3);
    int cf = (t & 7) * 8;                // f32 element offset in row
    bf16x8 v = cvt8(tile + row * 64 + cf);
    *(bf16x8*)(sm + row * 136 + cf) = v;
  }
  __syncthreads();

  // fragments from LDS
  const __bf16* myr = sm + (w * 16 + c) * 136;
  bf16x8 af0 = *(const bf16x8*)(myr + g * 8);
  bf16x8 af1 = *(const bf16x8*)(myr + 32 + g * 8);

  f32x4v acc[8];
#pragma unroll
  for (int nt = 0; nt < 8; ++nt) acc[nt] = (f32x4v)(0.f);
#pragma unroll
  for (int nt = 0; nt < 8; ++nt) {
    bf16x8 bf = *(const bf16x8*)(WTeb + (nt * 16 + c) * 64 + g * 8);
    acc[nt] = __builtin_amdgcn_mfma_f32_16x16x32_bf16(af0, bf, acc[nt], 0, 0, 0);
  }
#pragma unroll
  for (int nt = 0; nt < 8; ++nt) {
    bf16x8 bf = *(const bf16x8*)(WTeb + (nt * 16 + c) * 64 + 32 + g * 8);
    acc[nt] = __builtin_amdgcn_mfma_f32_16x16x32_bf16(af1, bf, acc[nt], 0, 0, 0);
  }

#pragma unroll
  for (int q = 0; q < 4; ++q) {
    int src = g * 4 + q;                 // wave-edge owning lane
    int row = __shfl(myrow, src, 64);
    int pos = __shfl(mypos, src, 64);
    bf16x8 yv = *(const bf16x8*)(Yb + (size_t)row * 128 + c * 8);  // 16B gather
    float v0 = fmaxf(acc[0][q] + (float)yv[0], 0.f);
    float v1 = fmaxf(acc[1][q] + (float)yv[1], 0.f);
    float v2 = fmaxf(acc[2][q] + (float)yv[2], 0.f);
    float v3 = fmaxf(acc[3][q] + (float)yv[3], 0.f);
    float v4 = fmaxf(acc[4][q] + (float)yv[4], 0.f);
    float v5 = fmaxf(acc[5][q] + (float)yv[5], 0.f);
    float v6 = fmaxf(acc[6][q] + (float)yv[6], 0.f);
    float v7 = fmaxf(acc[7][q] + (float)yv[7], 0.f);
    unsigned lo = __builtin_amdgcn_cvt_pk_fp8_f32(v0, v1, 0, false);
    lo = __builtin_amdgcn_cvt_pk_fp8_f32(v2, v3, lo, true);
    unsigned hi = __builtin_amdgcn_cvt_pk_fp8_f32(v4, v5, 0, false);
    hi = __builtin_amdgcn_cvt_pk_fp8_f32(v6, v7, hi, true);
    u32x2v o; o[0] = lo; o[1] = hi;
    *(u32x2v*)(TMP8 + (size_t)pos * 128 + c * 8) = o;  // 8B, 128B/16-lane row
  }
}

// ================= R: streaming fp8 segment mean (4 rows / iter) ============
__global__ __launch_bounds__(256) void node_R(
    const unsigned int* __restrict__ TMP32,   // fp8 rows as 32 x u32
    const int* __restrict__ cnt,
    const int* __restrict__ offs,             // END offsets
    __bf16* __restrict__ meanb)               // pi-packed (elementwise)
{
  int node = blockIdx.x * 4 + (threadIdx.x >> 6);
  int lane = threadIdx.x & 63;
  int p = lane >> 4;               // row slot 0..3
  int cu = lane & 15;              // u32-pair column (8 fp8 features)
  int m = cnt[node];
  int start = offs[node] - m;
  float s0 = 0.f, s1 = 0.f, s2 = 0.f, s3 = 0.f;
  float s4 = 0.f, s5 = 0.f, s6 = 0.f, s7 = 0.f;
  int iters = (m + 3) >> 2;
  for (int j = 0; j < iters; ++j) {
    int r = 4 * j + p;
    if (r < m) {
      u32x2v uu = *(const u32x2v*)(TMP32 + (size_t)(start + r) * 32 + cu * 2);
      f32x2v l0 = __builtin_amdgcn_cvt_pk_f32_fp8(uu[0], false);
      f32x2v h0 = __builtin_amdgcn_cvt_pk_f32_fp8(uu[0], true);
      f32x2v l1 = __builtin_amdgcn_cvt_pk_f32_fp8(uu[1], false);
      f32x2v h1 = __builtin_amdgcn_cvt_pk_f32_fp8(uu[1], true);
      s0 += l0[0]; s1 += l0[1]; s2 += h0[0]; s3 += h0[1];
      s4 += l1[0]; s5 += l1[1]; s6 += h1[0]; s7 += h1[1];
    }
  }
  // combine row slots: lanes p*16+cu for p=0..3 hold same features
  s0 += __shfl_xor(s0, 16); s1 += __shfl_xor(s1, 16);
  s2 += __shfl_xor(s2, 16); s3 += __shfl_xor(s3, 16);
  s4 += __shfl_xor(s4, 16); s5 += __shfl_xor(s5, 16);
  s6 += __shfl_xor(s6, 16); s7 += __shfl_xor(s7, 16);
  s0 += __shfl_xor(s0, 32); s1 += __shfl_xor(s1, 32);
  s2 += __shfl_xor(s2, 32); s3 += __shfl_xor(s3, 32);
  s4 += __shfl_xor(s4, 32); s5 += __shfl_xor(s5, 32);
  s6 += __shfl_xor(s6, 32); s7 += __shfl_xor(s7, 32);
  if (p == 0) {
    float inv = 1.f / fmaxf((float)m, 1.f);
    bf16x8 o;
    o[0] = (__bf16)(s0 * inv); o[1] = (__bf16)(s1 * inv);
    o[2] = (__bf16)(s2 * inv); o[3] = (__bf16)(s3 * inv);
    o[4] = (__bf16)(s4 * inv); o[5] = (__bf16)(s5 * inv);
    o[6] = (__bf16)(s6 * inv); o[7] = (__bf16)(s7 * inv);
    *(bf16x8*)(meanb + (size_t)node * 128 + cu * 8) = o;
  }
}

// ================= fused h1 + out GEMM ======================================
// meanb is pi-packed; WT2d rows were k-permuted in prep to match.
__global__ __launch_bounds__(256) void mlp_h1out(
    const float* __restrict__ x, const __bf16* __restrict__ meanb,
    const __bf16* __restrict__ WT2c, const __bf16* __restrict__ WT2d,
    const __bf16* __restrict__ WT2bT,
    const int* __restrict__ cnt, const float* __restrict__ b2a,
    const float* __restrict__ bc, const float* __restrict__ vtab,
    const int* __restrict__ batch, const float* __restrict__ b2b,
    float* __restrict__ out)
{
  __shared__ __bf16 ht[64 * 136];
  int lane = threadIdx.x & 63;
  int w = threadIdx.x >> 6;
  int rowbase = blockIdx.x * 64 + w * 16;
  int g = lane >> 4, c = lane & 15;

  f32x4v acc[8];
#pragma unroll
  for (int nt = 0; nt < 8; ++nt) acc[nt] = (f32x4v)(0.f);

  const float* arow = x + (size_t)(rowbase + c) * 128;
#pragma unroll
  for (int kk = 0; kk < 128; kk += 32) {
    bf16x8 af = cvt8(arow + kk + g * 8);
#pragma unroll
    for (int nt = 0; nt < 8; ++nt) {
      bf16x8 bf = *(const bf16x8*)(WT2c + (nt * 16 + c) * 128 + kk + g * 8);
      acc[nt] = __builtin_amdgcn_mfma_f32_16x16x32_bf16(af, bf, acc[nt], 0, 0, 0);
    }
  }
  const __bf16* arow2 = meanb + (size_t)(rowbase + c) * 128;
#pragma unroll
  for (int kk = 0; kk < 128; kk += 32) {
    bf16x8 af = *(const bf16x8*)(arow2 + kk + g * 8);
#pragma unroll
    for (int nt = 0; nt < 8; ++nt) {
      bf16x8 bf = *(const bf16x8*)(WT2d + (nt * 16 + c) * 128 + kk + g * 8);
      acc[nt] = __builtin_amdgcn_mfma_f32_16x16x32_bf16(af, bf, acc[nt], 0, 0, 0);
    }
  }

#pragma unroll
  for (int q = 0; q < 4; ++q) {
    int r = rowbase + g * 4 + q;
    float gmul = cnt[r] ? 1.f : 0.f;
    const float* vrow = vtab + (size_t)batch[r] * 128;
#pragma unroll
    for (int nt = 0; nt < 8; ++nt) {
      int n = nt * 16 + c;
      float v = acc[nt][q] + b2a[n] + gmul * bc[n] + vrow[n];
      ht[(w * 16 + g * 4 + q) * 136 + n] = (__bf16)fmaxf(v, 0.f);
    }
  }
  __syncthreads();

  f32x4v acc2[8];
#pragma unroll
  for (int nt = 0; nt < 8; ++nt) acc2[nt] = (f32x4v)(0.f);

  const __bf16* hrow = ht + (w * 16 + c) * 136;
#pragma unroll
  for (int kk = 0; kk < 128; kk += 32) {
    bf16x8 af = *(const bf16x8*)(hrow + kk + g * 8);
#pragma unroll
    for (int nt = 0; nt < 8; ++nt) {
      bf16x8 bf = *(const bf16x8*)(WT2bT + (nt * 16 + c) * 128 + kk + g * 8);
      acc2[nt] = __builtin_amdgcn_mfma_f32_16x16x32_bf16(af, bf, acc2[nt], 0, 0, 0);
    }
  }
#pragma unroll
  for (int q = 0; q < 4; ++q) {
    int r = rowbase + g * 4 + q;
#pragma unroll
    for (int nt = 0; nt < 8; ++nt) {
      int n = nt * 16 + c;
      out[(size_t)r * 128 + n] = acc2[nt][q] + b2b[n];
    }
  }
}

// ================= host =====================================================
extern "C" void kernel_launch(void* const* d_in, const int* in_sizes, int n_in,
                              void* d_out, int out_size, void* d_ws, size_t ws_size,
                              hipStream_t stream) {
  const float* x    = (const float*)d_in[0];
  const int*   ei   = (const int*)d_in[1];
  const float* ea   = (const float*)d_in[2];
  const float* u    = (const float*)d_in[3];
  const int*   batch= (const int*)d_in[4];
  const float* W1a  = (const float*)d_in[5];
  const float* b1a  = (const float*)d_in[6];
  const float* W1b  = (const float*)d_in[7];
  const float* b1b  = (const float*)d_in[8];
  const float* W2a  = (const float*)d_in[9];
  const float* b2a  = (const float*)d_in[10];
  const float* W2b  = (const float*)d_in[11];
  const float* b2b  = (const float*)d_in[12];

  char* ws = (char*)d_ws;
  __bf16* WTya  = (__bf16*)(ws);              // 32768
  __bf16* WTeb  = (__bf16*)(ws + 32768);      // 16384
  __bf16* WT2c  = (__bf16*)(ws + 49152);      // 32768
  __bf16* WT2bT = (__bf16*)(ws + 81920);      // 32768
  __bf16* WT2d  = (__bf16*)(ws + 114688);     // 32768
  float*  vtab  = (float*)(ws + 147456);      // 32768
  float*  bc    = (float*)(ws + 180224);      // 512
  int*    cnt   = (int*)(ws + 180736);        // 160,000
  int*    offs  = (int*)(ws + 340736);        // 160,000
  int*    bsum  = (int*)(ws + 500736);        // 1,024
  __bf16* Yb    = (__bf16*)(ws + 3061760);    // 10,240,000 (then meanb)
  unsigned char* TMP8 = (unsigned char*)(ws + 13301760); // 81,920,000 -> 95.2 MB
  __bf16* meanb = Yb;

  hipMemsetAsync(cnt, 0, 160000, stream);
  prep_hist<<<2885, 256, 0, stream>>>(W1a, W2a, W2b, W1b, b1b, u, ei,
                                      WTya, WTeb, WT2c, WT2bT, WT2d,
                                      vtab, bc, cnt);
  scanA<<<157, 256, 0, stream>>>(cnt, offs, bsum);
  scanBC_gemmy<<<782, 256, 0, stream>>>(offs, bsum, x, WTya, b1a, Yb);
  edge_E<<<NE / 64, 256, 0, stream>>>(ea, ei, offs, WTeb, Yb, TMP8);
  node_R<<<NN / 4, 256, 0, stream>>>((const unsigned int*)TMP8, cnt, offs, meanb);
  mlp_h1out<<<625, 256, 0, stream>>>(x, meanb, WT2c, WT2d, WT2bT,
                                     cnt, b2a, bc, vtab, batch, b2b,
                                     (float*)d_out);
}

// Round 13
// 221.102 us; speedup vs baseline: 1.3087x; 1.0273x over previous
//
#include <hip/hip_runtime.h>
#include <hip/hip_bf16.h>

// NodeModel fused GNN block, round 13.
//   = round 12 + (a) software-pipelined edge_E: 8 tiles/block, double-buffered
//     LDS, next-tile global loads in flight during current-tile MFMA/epilogue;
//     (b) node_R fused into mlp_h1out (mean pre-phase -> LDS, wave-private).
//   memset cnt; prep_hist; scanA; [scanBC|gemm_y]; edge_E; mlp_h1out

typedef __bf16 bf16x8 __attribute__((ext_vector_type(8)));
typedef float f32x4v __attribute__((ext_vector_type(4)));
typedef float f32x2v __attribute__((ext_vector_type(2)));
typedef unsigned int u32x2v __attribute__((ext_vector_type(2)));

#define NN 40000
#define NE 640000
#define TPB 8   // tiles (of 64 edges) per edge_E block

__device__ inline bf16x8 cvt8(const float* __restrict__ p) {
  f32x4v a = *(const f32x4v*)p;
  f32x4v b = *(const f32x4v*)(p + 4);
  bf16x8 r;
  r[0] = (__bf16)a[0]; r[1] = (__bf16)a[1]; r[2] = (__bf16)a[2]; r[3] = (__bf16)a[3];
  r[4] = (__bf16)b[0]; r[5] = (__bf16)b[1]; r[6] = (__bf16)b[2]; r[7] = (__bf16)b[3];
  return r;
}

// ================= prep (blocks 0..384) + histogram (385..2884) =============
__global__ __launch_bounds__(256) void prep_hist(
    const float* __restrict__ W1a, const float* __restrict__ W2a,
    const float* __restrict__ W2b, const float* __restrict__ W1b,
    const float* __restrict__ b1b, const float* __restrict__ u,
    const int* __restrict__ EI,
    __bf16* __restrict__ WTya, __bf16* __restrict__ WTeb,
    __bf16* __restrict__ WT2c, __bf16* __restrict__ WT2bT,
    __bf16* __restrict__ WT2d, float* __restrict__ vtab,
    float* __restrict__ bc, int* __restrict__ cnt)
{
  int b = blockIdx.x, t = threadIdx.x;
  if (b >= 385) {                     // histogram: 2500 blocks cover NE
    int e = (b - 385) * 256 + t;
    atomicAdd(&cnt[EI[NE + e]], 1);
    return;
  }
  if (b < 64) {
    int idx = b * 256 + t; int n = idx & 127; int k = idx >> 7;
    WTya[n * 128 + k] = (__bf16)W1a[k * 128 + n];
  } else if (b < 96) {
    int idx = (b - 64) * 256 + t; int n = idx & 127; int k = idx >> 7;
    WTeb[n * 64 + k] = (__bf16)W1a[(128 + k) * 128 + n];
  } else if (b < 160) {
    int idx = (b - 96) * 256 + t; int n = idx & 127; int k = idx >> 7;
    WT2c[n * 128 + k] = (__bf16)W2a[k * 128 + n];
  } else if (b < 224) {
    int idx = (b - 160) * 256 + t; int n = idx & 127; int k = idx >> 7;
    WT2bT[n * 128 + k] = (__bf16)W2b[k * 128 + n];
  } else if (b < 256) {
    int idx = (b - 224) * 256 + t; int n = idx & 127; int gi = idx >> 7;
    float s0 = 0.f, s1 = 0.f;
    for (int k = 0; k < 64; k += 2) {
      s0 += u[gi * 64 + k] * W2a[(256 + k) * 128 + n];
      s1 += u[gi * 64 + k + 1] * W2a[(257 + k) * 128 + n];
    }
    vtab[gi * 128 + n] = s0 + s1;
  } else if (b == 256) {
    if (t < 128) {
      float s0 = 0.f, s1 = 0.f;
      for (int j = 0; j < 128; j += 2) {
        s0 += b1b[j] * W2a[(128 + j) * 128 + t];
        s1 += b1b[j + 1] * W2a[(129 + j) * 128 + t];
      }
      bc[t] = s0 + s1;
    }
  } else {
    int k = b - 257;                  // mean-feature index (pre-permute)
    if (t < 128) {
      float s0 = 0.f, s1 = 0.f;
      for (int j = 0; j < 128; j += 2) {
        s0 += W1b[k * 128 + j] * W2a[(128 + j) * 128 + t];
        s1 += W1b[k * 128 + j + 1] * W2a[(129 + j) * 128 + t];
      }
      int kp = ((k & 15) << 3) | (k >> 4);   // inverse of pi: pi(kp) == k
      WT2d[t * 128 + kp] = (__bf16)(s0 + s1);
    }
  }
}

// ================= scanA: block-local exclusive scan + block sums ===========
__global__ __launch_bounds__(256) void scanA(const int* __restrict__ cnt,
                                             int* __restrict__ offs,
                                             int* __restrict__ bsum) {
  __shared__ int sc[256];
  int i = blockIdx.x * 256 + threadIdx.x;
  int v = (i < NN) ? cnt[i] : 0;
  sc[threadIdx.x] = v;
  __syncthreads();
  for (int off = 1; off < 256; off <<= 1) {
    int t2 = (threadIdx.x >= off) ? sc[threadIdx.x - off] : 0;
    __syncthreads();
    sc[threadIdx.x] += t2;
    __syncthreads();
  }
  if (i < NN) offs[i] = sc[threadIdx.x] - v;      // exclusive within block
  if (threadIdx.x == 255) bsum[blockIdx.x] = sc[255];
}

// ================= fused: scanBC (blocks 0..156) | gemm_y (157..781) ========
__global__ __launch_bounds__(256) void scanBC_gemmy(
    int* __restrict__ offs, const int* __restrict__ bsum,
    const float* __restrict__ x, const __bf16* __restrict__ WTya,
    const float* __restrict__ b1a, __bf16* __restrict__ Yb)
{
  __shared__ int sc[256];
  if (blockIdx.x < 157) {
    int t = threadIdx.x;
    sc[t] = (t < 157) ? bsum[t] : 0;
    __syncthreads();
    for (int off = 1; off < 256; off <<= 1) {
      int t2 = (t >= off) ? sc[t - off] : 0;
      __syncthreads();
      sc[t] += t2;
      __syncthreads();
    }
    int base = (blockIdx.x > 0) ? sc[blockIdx.x - 1] : 0;
    int i = blockIdx.x * 256 + t;
    if (i < NN) offs[i] += base;
    return;
  }
  // ---- gemm_y: Yb (pi-packed) = x @ W1a_top + b1a ----
  int lane = threadIdx.x & 63;
  int wave = threadIdx.x >> 6;
  int rowbase = (blockIdx.x - 157) * 64 + wave * 16;
  int g = lane >> 4, c = lane & 15;

  f32x4v acc[8];
#pragma unroll
  for (int nt = 0; nt < 8; ++nt) acc[nt] = (f32x4v)(0.f);

  const float* arow = x + (size_t)(rowbase + c) * 128;
#pragma unroll
  for (int kk = 0; kk < 128; kk += 32) {
    bf16x8 af = cvt8(arow + kk + g * 8);
#pragma unroll
    for (int nt = 0; nt < 8; ++nt) {
      bf16x8 bf = *(const bf16x8*)(WTya + (nt * 16 + c) * 128 + kk + g * 8);
      acc[nt] = __builtin_amdgcn_mfma_f32_16x16x32_bf16(af, bf, acc[nt], 0, 0, 0);
    }
  }
  float bl[8];
#pragma unroll
  for (int nt = 0; nt < 8; ++nt) bl[nt] = b1a[nt * 16 + c];
#pragma unroll
  for (int q = 0; q < 4; ++q) {
    int r = rowbase + g * 4 + q;
    bf16x8 o;
#pragma unroll
    for (int nt = 0; nt < 8; ++nt) o[nt] = (__bf16)(acc[nt][q] + bl[nt]);
    *(bf16x8*)(Yb + (size_t)r * 128 + c * 8) = o;
  }
}

// ================= E: software-pipelined edge GEMM ==========================
// 8 tiles of 64 edges per block; double-buffered LDS staging; next tile's
// global loads issued before current tile's compute -> continuous HBM stream.
__global__ __launch_bounds__(256) void edge_E(
    const float* __restrict__ EA, const int* __restrict__ EI,
    int* __restrict__ offs,              // mutates to END offsets
    const __bf16* __restrict__ WTeb,
    const __bf16* __restrict__ Yb,       // pi-packed
    unsigned char* __restrict__ TMP8)    // 640000 x 128 fp8, pi-packed rows
{
  __shared__ __bf16 sm[2][64 * 136];
  int t = threadIdx.x;
  int lane = t & 63, w = t >> 6, g = lane >> 4, c = lane & 15;
  int r0 = t >> 3;                        // staging row 0..31
  int cf = (t & 7) * 8;                   // staging f32 col offset
  size_t blockEdge0 = (size_t)blockIdx.x * (64 * TPB);
  const float* gbase = EA + blockEdge0 * 64;

  f32x4v bufA[4], bufB[4];
  // prologue: load tile 0
#pragma unroll
  for (int j = 0; j < 2; ++j) {
    const float* p = gbase + (size_t)(j * 32 + r0) * 64 + cf;
    bufA[2 * j] = *(const f32x4v*)p;
    bufA[2 * j + 1] = *(const f32x4v*)(p + 4);
  }

  for (int tile = 0; tile < TPB; ++tile) {
    // stage bufA -> sm[tile&1] (bf16, padded rows)
    __bf16* s = &sm[tile & 1][0];
#pragma unroll
    for (int j = 0; j < 2; ++j) {
      f32x4v a = bufA[2 * j], b = bufA[2 * j + 1];
      bf16x8 v;
      v[0] = (__bf16)a[0]; v[1] = (__bf16)a[1]; v[2] = (__bf16)a[2]; v[3] = (__bf16)a[3];
      v[4] = (__bf16)b[0]; v[5] = (__bf16)b[1]; v[6] = (__bf16)b[2]; v[7] = (__bf16)b[3];
      *(bf16x8*)(s + (j * 32 + r0) * 136 + cf) = v;
    }
    // issue next tile's loads (stay in flight through this tile's compute)
    if (tile + 1 < TPB) {
      const float* tp = gbase + (size_t)(tile + 1) * 64 * 64;
#pragma unroll
      for (int j = 0; j < 2; ++j) {
        const float* p = tp + (size_t)(j * 32 + r0) * 64 + cf;
        bufB[2 * j] = *(const f32x4v*)p;
        bufB[2 * j + 1] = *(const f32x4v*)(p + 4);
      }
    }
    // edge meta + sorted-slot alloc
    int e0 = (int)blockEdge0 + tile * 64 + w * 16;
    int myrow = 0, mypos = 0;
    if (lane < 16) {
      myrow = EI[e0 + lane];
      mypos = atomicAdd(&offs[EI[NE + e0 + lane]], 1);
    }
    __syncthreads();                     // sm[tile&1] ready for all waves

    const __bf16* myr = s + (w * 16 + c) * 136;
    bf16x8 af0 = *(const bf16x8*)(myr + g * 8);
    bf16x8 af1 = *(const bf16x8*)(myr + 32 + g * 8);

    f32x4v acc[8];
#pragma unroll
    for (int nt = 0; nt < 8; ++nt) acc[nt] = (f32x4v)(0.f);
#pragma unroll
    for (int nt = 0; nt < 8; ++nt) {
      bf16x8 bf = *(const bf16x8*)(WTeb + (nt * 16 + c) * 64 + g * 8);
      acc[nt] = __builtin_amdgcn_mfma_f32_16x16x32_bf16(af0, bf, acc[nt], 0, 0, 0);
    }
#pragma unroll
    for (int nt = 0; nt < 8; ++nt) {
      bf16x8 bf = *(const bf16x8*)(WTeb + (nt * 16 + c) * 64 + 32 + g * 8);
      acc[nt] = __builtin_amdgcn_mfma_f32_16x16x32_bf16(af1, bf, acc[nt], 0, 0, 0);
    }

#pragma unroll
    for (int q = 0; q < 4; ++q) {
      int src = g * 4 + q;               // wave-edge owning lane
      int row = __shfl(myrow, src, 64);
      int pos = __shfl(mypos, src, 64);
      bf16x8 yv = *(const bf16x8*)(Yb + (size_t)row * 128 + c * 8);
      float v0 = fmaxf(acc[0][q] + (float)yv[0], 0.f);
      float v1 = fmaxf(acc[1][q] + (float)yv[1], 0.f);
      float v2 = fmaxf(acc[2][q] + (float)yv[2], 0.f);
      float v3 = fmaxf(acc[3][q] + (float)yv[3], 0.f);
      float v4 = fmaxf(acc[4][q] + (float)yv[4], 0.f);
      float v5 = fmaxf(acc[5][q] + (float)yv[5], 0.f);
      float v6 = fmaxf(acc[6][q] + (float)yv[6], 0.f);
      float v7 = fmaxf(acc[7][q] + (float)yv[7], 0.f);
      unsigned lo = __builtin_amdgcn_cvt_pk_fp8_f32(v0, v1, 0, false);
      lo = __builtin_amdgcn_cvt_pk_fp8_f32(v2, v3, lo, true);
      unsigned hi = __builtin_amdgcn_cvt_pk_fp8_f32(v4, v5, 0, false);
      hi = __builtin_amdgcn_cvt_pk_fp8_f32(v6, v7, hi, true);
      u32x2v o; o[0] = lo; o[1] = hi;
      *(u32x2v*)(TMP8 + (size_t)pos * 128 + c * 8) = o;
    }

    if (tile + 1 < TPB) {
#pragma unroll
      for (int k = 0; k < 4; ++k) bufA[k] = bufB[k];
    }
  }
}

// ================= fused mean + h1 + out GEMM ===============================
// Phase A: per-wave compute 16 node-means from TMP8 -> LDS (pi-packed).
// Phase B: acc = x@WT2c + mean@WT2d; h1 -> same LDS (wave-private regions).
// Phase C: out = h1 @ WT2bT + b2b.  No barriers needed (all LDS wave-private).
__global__ __launch_bounds__(256) void mlp_h1out(
    const unsigned int* __restrict__ TMP32,   // fp8 rows as 32 x u32
    const int* __restrict__ cnt, const int* __restrict__ offs,
    const float* __restrict__ x,
    const __bf16* __restrict__ WT2c, const __bf16* __restrict__ WT2d,
    const __bf16* __restrict__ WT2bT,
    const float* __restrict__ b2a, const float* __restrict__ bc,
    const float* __restrict__ vtab, const int* __restrict__ batch,
    const float* __restrict__ b2b, float* __restrict__ out)
{
  __shared__ __bf16 sb[64 * 136];       // mean (phase A/B), then h1 (B/C)
  int lane = threadIdx.x & 63;
  int w = threadIdx.x >> 6;
  int rowbase = blockIdx.x * 64 + w * 16;
  int g = lane >> 4, c = lane & 15;

  // ---- phase A: mean for this wave's 16 nodes ----
  {
    int p = lane >> 4, cu = lane & 15;  // row-slot 0..3, u32-pair col 0..15
    for (int nn = 0; nn < 16; ++nn) {
      int node = rowbase + nn;
      int m = cnt[node];
      int start = offs[node] - m;
      float s0 = 0.f, s1 = 0.f, s2 = 0.f, s3 = 0.f;
      float s4 = 0.f, s5 = 0.f, s6 = 0.f, s7 = 0.f;
      int iters = (m + 3) >> 2;
      for (int j = 0; j < iters; ++j) {
        int r = 4 * j + p;
        if (r < m) {
          u32x2v uu = *(const u32x2v*)(TMP32 + (size_t)(start + r) * 32 + cu * 2);
          f32x2v l0 = __builtin_amdgcn_cvt_pk_f32_fp8(uu[0], false);
          f32x2v h0 = __builtin_amdgcn_cvt_pk_f32_fp8(uu[0], true);
          f32x2v l1 = __builtin_amdgcn_cvt_pk_f32_fp8(uu[1], false);
          f32x2v h1 = __builtin_amdgcn_cvt_pk_f32_fp8(uu[1], true);
          s0 += l0[0]; s1 += l0[1]; s2 += h0[0]; s3 += h0[1];
          s4 += l1[0]; s5 += l1[1]; s6 += h1[0]; s7 += h1[1];
        }
      }
      s0 += __shfl_xor(s0, 16); s1 += __shfl_xor(s1, 16);
      s2 += __shfl_xor(s2, 16); s3 += __shfl_xor(s3, 16);
      s4 += __shfl_xor(s4, 16); s5 += __shfl_xor(s5, 16);
      s6 += __shfl_xor(s6, 16); s7 += __shfl_xor(s7, 16);
      s0 += __shfl_xor(s0, 32); s1 += __shfl_xor(s1, 32);
      s2 += __shfl_xor(s2, 32); s3 += __shfl_xor(s3, 32);
      s4 += __shfl_xor(s4, 32); s5 += __shfl_xor(s5, 32);
      s6 += __shfl_xor(s6, 32); s7 += __shfl_xor(s7, 32);
      if (p == 0) {
        float inv = 1.f / fmaxf((float)m, 1.f);
        bf16x8 o;
        o[0] = (__bf16)(s0 * inv); o[1] = (__bf16)(s1 * inv);
        o[2] = (__bf16)(s2 * inv); o[3] = (__bf16)(s3 * inv);
        o[4] = (__bf16)(s4 * inv); o[5] = (__bf16)(s5 * inv);
        o[6] = (__bf16)(s6 * inv); o[7] = (__bf16)(s7 * inv);
        *(bf16x8*)(sb + (w * 16 + nn) * 136 + cu * 8) = o;
      }
    }
  }

  // ---- phase B: acc = x@WT2c + mean@WT2d ----
  f32x4v acc[8];
#pragma unroll
  for (int nt = 0; nt < 8; ++nt) acc[nt] = (f32x4v)(0.f);

  const float* arow = x + (size_t)(rowbase + c) * 128;
#pragma unroll
  for (int kk = 0; kk < 128; kk += 32) {
    bf16x8 af = cvt8(arow + kk + g * 8);
#pragma unroll
    for (int nt = 0; nt < 8; ++nt) {
      bf16x8 bf = *(const bf16x8*)(WT2c + (nt * 16 + c) * 128 + kk + g * 8);
      acc[nt] = __builtin_amdgcn_mfma_f32_16x16x32_bf16(af, bf, acc[nt], 0, 0, 0);
    }
  }
  const __bf16* mrow = sb + (w * 16 + c) * 136;   // pi-packed mean (own wave)
#pragma unroll
  for (int kk = 0; kk < 128; kk += 32) {
    bf16x8 af = *(const bf16x8*)(mrow + kk + g * 8);
#pragma unroll
    for (int nt = 0; nt < 8; ++nt) {
      bf16x8 bf = *(const bf16x8*)(WT2d + (nt * 16 + c) * 128 + kk + g * 8);
      acc[nt] = __builtin_amdgcn_mfma_f32_16x16x32_bf16(af, bf, acc[nt], 0, 0, 0);
    }
  }

  // h1 = relu(acc + b2a + gate*bc + vtab[batch]) -> sb (own wave rows)
#pragma unroll
  for (int q = 0; q < 4; ++q) {
    int r = rowbase + g * 4 + q;
    float gmul = cnt[r] ? 1.f : 0.f;
    const float* vrow = vtab + (size_t)batch[r] * 128;
#pragma unroll
    for (int nt = 0; nt < 8; ++nt) {
      int n = nt * 16 + c;
      float v = acc[nt][q] + b2a[n] + gmul * bc[n] + vrow[n];
      sb[(w * 16 + g * 4 + q) * 136 + n] = (__bf16)fmaxf(v, 0.f);
    }
  }

  // ---- phase C: out = h1 @ WT2bT + b2b ----
  f32x4v acc2[8];
#pragma unroll
  for (int nt = 0; nt < 8; ++nt) acc2[nt] = (f32x4v)(0.f);

  const __bf16* hrow = sb + (w * 16 + c) * 136;
#pragma unroll
  for (int kk = 0; kk < 128; kk += 32) {
    bf16x8 af = *(const bf16x8*)(hrow + kk + g * 8);
#pragma unroll
    for (int nt = 0; nt < 8; ++nt) {
      bf16x8 bf = *(const bf16x8*)(WT2bT + (nt * 16 + c) * 128 + kk + g * 8);
      acc2[nt] = __builtin_amdgcn_mfma_f32_16x16x32_bf16(af, bf, acc2[nt], 0, 0, 0);
    }
  }
#pragma unroll
  for (int q = 0; q < 4; ++q) {
    int r = rowbase + g * 4 + q;
#pragma unroll
    for (int nt = 0; nt < 8; ++nt) {
      int n = nt * 16 + c;
      out[(size_t)r * 128 + n] = acc2[nt][q] + b2b[n];
    }
  }
}

// ================= host =====================================================
extern "C" void kernel_launch(void* const* d_in, const int* in_sizes, int n_in,
                              void* d_out, int out_size, void* d_ws, size_t ws_size,
                              hipStream_t stream) {
  const float* x    = (const float*)d_in[0];
  const int*   ei   = (const int*)d_in[1];
  const float* ea   = (const float*)d_in[2];
  const float* u    = (const float*)d_in[3];
  const int*   batch= (const int*)d_in[4];
  const float* W1a  = (const float*)d_in[5];
  const float* b1a  = (const float*)d_in[6];
  const float* W1b  = (const float*)d_in[7];
  const float* b1b  = (const float*)d_in[8];
  const float* W2a  = (const float*)d_in[9];
  const float* b2a  = (const float*)d_in[10];
  const float* W2b  = (const float*)d_in[11];
  const float* b2b  = (const float*)d_in[12];

  char* ws = (char*)d_ws;
  __bf16* WTya  = (__bf16*)(ws);              // 32768
  __bf16* WTeb  = (__bf16*)(ws + 32768);      // 16384
  __bf16* WT2c  = (__bf16*)(ws + 49152);      // 32768
  __bf16* WT2bT = (__bf16*)(ws + 81920);      // 32768
  __bf16* WT2d  = (__bf16*)(ws + 114688);     // 32768
  float*  vtab  = (float*)(ws + 147456);      // 32768
  float*  bc    = (float*)(ws + 180224);      // 512
  int*    cnt   = (int*)(ws + 180736);        // 160,000
  int*    offs  = (int*)(ws + 340736);        // 160,000
  int*    bsum  = (int*)(ws + 500736);        // 1,024
  __bf16* Yb    = (__bf16*)(ws + 3061760);    // 10,240,000
  unsigned char* TMP8 = (unsigned char*)(ws + 13301760); // 81,920,000 -> 95.2 MB

  hipMemsetAsync(cnt, 0, 160000, stream);
  prep_hist<<<2885, 256, 0, stream>>>(W1a, W2a, W2b, W1b, b1b, u, ei,
                                      WTya, WTeb, WT2c, WT2bT, WT2d,
                                      vtab, bc, cnt);
  scanA<<<157, 256, 0, stream>>>(cnt, offs, bsum);
  scanBC_gemmy<<<782, 256, 0, stream>>>(offs, bsum, x, WTya, b1a, Yb);
  edge_E<<<NE / (64 * TPB), 256, 0, stream>>>(ea, ei, offs, WTeb, Yb, TMP8);
  mlp_h1out<<<625, 256, 0, stream>>>((const unsigned int*)TMP8, cnt, offs, x,
                                     WT2c, WT2d, WT2bT, b2a, bc, vtab, batch,
                                     b2b, (float*)d_out);
}